// Round 2
// baseline (206.162 us; speedup 1.0000x reference)
//
#include <hip/hip_runtime.h>

// Problem constants (from reference setup_inputs)
constexpr int Bn  = 256;   // batch
constexpr int Nn  = 16;    // template children
constexpr int Mn  = 128;   // sequence length
constexpr int Vn  = 64;    // vocab
constexpr int Hn  = 128;   // hidden
constexpr int Kn  = 8;     // template rows
constexpr int NP1 = 17;    // N+1
constexpr int KN  = Kn * NP1; // 136

// K2: one block per (b,k). Compute template selection (argmax_n logits+gumbel)
// and the selected row's effective length. 128 threads: 1 thread per position.
__global__ __launch_bounds__(128) void select_and_len(
    const float* __restrict__ dec,       // [B,N,M,V]
    const float* __restrict__ type_emb,  // [T,H]
    const float* __restrict__ w_sem,     // [15, K*(N+1), H]
    const float* __restrict__ b_sem,     // [15, K*(N+1)]
    const float* __restrict__ gumbel,    // [B,K,N+1]
    const int*   __restrict__ ttypes,    // [B]
    const int*   __restrict__ spans,     // [B]
    int*         __restrict__ sel_out,   // [B,K]
    int*         __restrict__ len_out)   // [B,K]
{
    const int bk  = blockIdx.x;          // b*K + k
    const int b   = bk >> 3;
    const int k   = bk & 7;
    const int tid = threadIdx.x;
    const int lane = tid & 63;
    const int wave = tid >> 6;

    __shared__ float s_scores[NP1];
    __shared__ int   s_sel;
    __shared__ int   s_wmax[2];

    const int t = ttypes[b];

    if (t == 20) {
        if (tid == 0) s_sel = (k == 0) ? 1 : 0;  // start template: row0->child1, rest pad
    } else {
        const int span = spans[b];
        if (tid < NP1) {
            float score = -1e30f;
            if (tid <= span) {
                const int row = k * NP1 + tid;
                const float4* wrow = (const float4*)(w_sem + ((size_t)(t - 9) * KN + row) * Hn);
                const float4* erow = (const float4*)(type_emb + (size_t)t * Hn);
                float acc = 0.f;
                #pragma unroll
                for (int i = 0; i < Hn / 4; ++i) {
                    float4 wv = wrow[i];
                    float4 ev = erow[i];
                    acc += wv.x * ev.x + wv.y * ev.y + wv.z * ev.z + wv.w * ev.w;
                }
                score = acc + b_sem[(t - 9) * KN + row] + gumbel[(size_t)b * KN + row];
            }
            s_scores[tid] = score;
        }
        __syncthreads();
        if (tid == 0) {
            int best = 0;
            float bv = s_scores[0];
            #pragma unroll
            for (int n = 1; n < NP1; ++n) {
                float v = s_scores[n];
                if (v > bv) { bv = v; best = n; }   // first-max tie-break (strict >)
            }
            s_sel = best;
        }
    }
    __syncthreads();

    const int s = s_sel;
    // len = max_m( m+1 if argmax_v(row[m]) != 0 ), where argmax!=0 <=> max(v[1..]) > v[0]
    int local = 0;
    if (s > 0) {
        const int m = tid;  // 128 threads, 128 positions
        const float4* p = (const float4*)(dec + (((size_t)b * Nn + (s - 1)) * Mn + m) * Vn);
        float4 v0 = p[0];
        float mx = fmaxf(fmaxf(v0.y, v0.z), v0.w);
        #pragma unroll
        for (int j = 1; j < Vn / 4; ++j) {
            float4 v = p[j];
            mx = fmaxf(mx, fmaxf(fmaxf(v.x, v.y), fmaxf(v.z, v.w)));
        }
        if (mx > v0.x) local = m + 1;   // strict: index 0 wins ties (first-max)
    }
    #pragma unroll
    for (int d = 32; d > 0; d >>= 1)
        local = max(local, __shfl_xor(local, d, 64));
    if (lane == 0) s_wmax[wave] = local;
    __syncthreads();
    if (tid == 0) {
        len_out[bk] = max(s_wmax[0], s_wmax[1]);
        sel_out[bk] = s;
    }
}

// K3: one block per (b,k). Redundant 8-step offset scan, copy own segment,
// interleaved zero-fill of the tail.
__global__ __launch_bounds__(256) void pack_copy(
    const float* __restrict__ dec,     // [B,N,M,V]
    const int*   __restrict__ sel,     // [B,K]
    const int*   __restrict__ len,     // [B,K]
    float*       __restrict__ out)     // [B,M,V]
{
    const int bk  = blockIdx.x;
    const int b   = bk >> 3;
    const int k   = bk & 7;
    const int tid = threadIdx.x;

    // sequential packing scan (trivially redundant per thread; len is L1/L2-hot)
    int idx = 0, myoff = 0, myeff = 0;
    #pragma unroll
    for (int j = 0; j < Kn; ++j) {
        const int l = len[b * Kn + j];
        const int e = min(l, Mn - idx);
        if (j == k) { myoff = idx; myeff = e; }
        idx += e;
    }
    const int total = idx;

    float4* outb = (float4*)(out + (size_t)b * Mn * Vn);

    if (myeff > 0) {
        const int s = sel[b * Kn + k];   // myeff>0 implies s>0
        const float4* src = (const float4*)(dec + (((size_t)b * Nn + (s - 1)) * Mn) * Vn);
        float4* dst = outb + (size_t)myoff * (Vn / 4);
        const int cnt = myeff * (Vn / 4);
        for (int i = tid; i < cnt; i += 256) dst[i] = src[i];
    }

    // zero-fill tail rows [total, Mn) — the 8 blocks of this b interleave chunks
    const int zcnt = (Mn - total) * (Vn / 4);
    float4* z = outb + (size_t)total * (Vn / 4);
    const float4 zero = make_float4(0.f, 0.f, 0.f, 0.f);
    for (int i = tid + 256 * k; i < zcnt; i += 256 * Kn) z[i] = zero;
}

extern "C" void kernel_launch(void* const* d_in, const int* in_sizes, int n_in,
                              void* d_out, int out_size, void* d_ws, size_t ws_size,
                              hipStream_t stream) {
    const float* dec      = (const float*)d_in[0];
    const float* type_emb = (const float*)d_in[1];
    const float* w_sem    = (const float*)d_in[2];
    const float* b_sem    = (const float*)d_in[3];
    const float* gumbel   = (const float*)d_in[4];
    const int*   ttypes   = (const int*)d_in[5];
    const int*   spans    = (const int*)d_in[6];
    float* out = (float*)d_out;

    int* sel_ws = (int*)d_ws;                 // [B*K]
    int* len_ws = sel_ws + Bn * Kn;           // [B*K]

    select_and_len<<<Bn * Kn, 128, 0, stream>>>(
        dec, type_emb, w_sem, b_sem, gumbel, ttypes, spans, sel_ws, len_ws);
    pack_copy<<<Bn * Kn, 256, 0, stream>>>(dec, sel_ws, len_ws, out);
}

// Round 3
// 192.172 us; speedup vs baseline: 1.0728x; 1.0728x over previous
//
#include <hip/hip_runtime.h>

// Problem constants (from reference setup_inputs)
constexpr int Bn  = 256;   // batch
constexpr int Nn  = 16;    // template children
constexpr int Mn  = 128;   // sequence length
constexpr int Vn  = 64;    // vocab
constexpr int Hn  = 128;   // hidden
constexpr int Kn  = 8;     // template rows
constexpr int NP1 = 17;    // N+1
constexpr int KN  = Kn * NP1; // 136

// One block per batch element, 1024 threads = 16 waves.
// wave w handles template row k = w/2, half = w%2; lane l -> position m = half*64 + l.
// Each lane keeps its full V=64 vector in registers (16 float4) between the
// length pass and the packed write -> selected rows are read from HBM exactly once.
__global__ __launch_bounds__(1024) void fused_one_pass(
    const float* __restrict__ dec,       // [B,N,M,V]
    const float* __restrict__ type_emb,  // [T,H]
    const float* __restrict__ w_sem,     // [15, K*(N+1), H]
    const float* __restrict__ b_sem,     // [15, K*(N+1)]
    const float* __restrict__ gumbel,    // [B,K,N+1]
    const int*   __restrict__ ttypes,    // [B]
    const int*   __restrict__ spans,     // [B]
    float*       __restrict__ out)       // [B,M,V]
{
    const int b    = blockIdx.x;
    const int tid  = threadIdx.x;
    const int lane = tid & 63;
    const int wave = tid >> 6;
    const int k    = wave >> 1;
    const int m    = ((wave & 1) << 6) | lane;   // position 0..127

    __shared__ float s_scores[KN];
    __shared__ int   s_sel[Kn];
    __shared__ int   s_wlen[16];
    __shared__ int   s_off[Kn];
    __shared__ int   s_eff[Kn];
    __shared__ int   s_total;

    const int t = ttypes[b];

    // ---- Phase 1: template selection (argmax_n of logits + gumbel) ----
    if (t == 20) {
        if (tid < Kn) s_sel[tid] = (tid == 0) ? 1 : 0;  // start template
    } else {
        const int span = spans[b];
        if (tid < KN) {
            const int n = tid % NP1;
            float score = -1e30f;
            if (n <= span) {
                const float4* wrow = (const float4*)(w_sem + ((size_t)(t - 9) * KN + tid) * Hn);
                const float4* erow = (const float4*)(type_emb + (size_t)t * Hn);
                float acc = 0.f;
                #pragma unroll
                for (int i = 0; i < Hn / 4; ++i) {
                    float4 wv = wrow[i];
                    float4 ev = erow[i];
                    acc += wv.x * ev.x + wv.y * ev.y + wv.z * ev.z + wv.w * ev.w;
                }
                score = acc + b_sem[(t - 9) * KN + tid] + gumbel[(size_t)b * KN + tid];
            }
            s_scores[tid] = score;
        }
        __syncthreads();
        if (tid < Kn) {
            int best = 0;
            float bv = s_scores[tid * NP1];
            #pragma unroll
            for (int n = 1; n < NP1; ++n) {
                float v = s_scores[tid * NP1 + n];
                if (v > bv) { bv = v; best = n; }   // first-max tie-break (strict >)
            }
            s_sel[tid] = best;
        }
    }
    __syncthreads();

    // ---- Phase 2: load row into registers + effective length ----
    const int s = s_sel[k];
    float4 data[16];
    int mylen = 0;
    if (s > 0) {
        const float4* p = (const float4*)(dec + (((size_t)b * Nn + (s - 1)) * Mn + m) * Vn);
        #pragma unroll
        for (int j = 0; j < Vn / 4; ++j) data[j] = p[j];
        // argmax_v != 0  <=>  max(v[1..63]) > v[0]  (first-max tie-break)
        float mx = fmaxf(fmaxf(data[0].y, data[0].z), data[0].w);
        #pragma unroll
        for (int j = 1; j < Vn / 4; ++j) {
            float4 v = data[j];
            mx = fmaxf(mx, fmaxf(fmaxf(v.x, v.y), fmaxf(v.z, v.w)));
        }
        if (mx > data[0].x) mylen = m + 1;
    }
    #pragma unroll
    for (int d = 32; d > 0; d >>= 1)
        mylen = max(mylen, __shfl_xor(mylen, d, 64));
    if (lane == 0) s_wlen[wave] = mylen;
    __syncthreads();

    // ---- Phase 3: sequential packing scan over K=8 ----
    if (tid == 0) {
        int idx = 0;
        #pragma unroll
        for (int j = 0; j < Kn; ++j) {
            const int l = max(s_wlen[2 * j], s_wlen[2 * j + 1]);
            const int e = min(l, Mn - idx);
            s_off[j] = idx;
            s_eff[j] = e;
            idx += e;
        }
        s_total = idx;
    }
    __syncthreads();

    // ---- Phase 4: packed write straight from registers ----
    if (s > 0 && m < s_eff[k]) {
        float4* dst = (float4*)(out + ((size_t)b * Mn + s_off[k] + m) * Vn);
        #pragma unroll
        for (int j = 0; j < Vn / 4; ++j) dst[j] = data[j];
    }

    // ---- Phase 5: zero-fill tail rows [total, Mn) ----
    const int total = s_total;
    const int zcnt  = (Mn - total) * (Vn / 4);
    float4* z = (float4*)(out + ((size_t)b * Mn + total) * Vn);
    const float4 zero = make_float4(0.f, 0.f, 0.f, 0.f);
    for (int i = tid; i < zcnt; i += 1024) z[i] = zero;
}

extern "C" void kernel_launch(void* const* d_in, const int* in_sizes, int n_in,
                              void* d_out, int out_size, void* d_ws, size_t ws_size,
                              hipStream_t stream) {
    const float* dec      = (const float*)d_in[0];
    const float* type_emb = (const float*)d_in[1];
    const float* w_sem    = (const float*)d_in[2];
    const float* b_sem    = (const float*)d_in[3];
    const float* gumbel   = (const float*)d_in[4];
    const int*   ttypes   = (const int*)d_in[5];
    const int*   spans    = (const int*)d_in[6];
    float* out = (float*)d_out;

    fused_one_pass<<<Bn, 1024, 0, stream>>>(
        dec, type_emb, w_sem, b_sem, gumbel, ttypes, spans, out);
}